// Round 19
// baseline (3614.733 us; speedup 1.0000x reference)
//
#include <hip/hip_runtime.h>
#include <cstdint>
#include <cstddef>

#define T_STEPS 2048
#define BATCH 64

typedef _Float16 f16;
typedef _Float16 f16x2 __attribute__((ext_vector_type(2)));
typedef _Float16 f16x8 __attribute__((ext_vector_type(8)));
typedef float f32x4 __attribute__((ext_vector_type(4)));
typedef unsigned int uint32;
typedef unsigned long long uint64;
typedef uint32 u32x4 __attribute__((ext_vector_type(4)));

__device__ __forceinline__ float dot2(uint32 w, uint32 h, float c) {
  f16x2 a = __builtin_bit_cast(f16x2, w);
  f16x2 b = __builtin_bit_cast(f16x2, h);
  return __builtin_amdgcn_fdot2(a, b, c, false);
}

__device__ __forceinline__ float dot8(u32x4 w, u32x4 h, float c) {
  c = dot2(w[0], h[0], c);
  c = dot2(w[1], h[1], c);
  c = dot2(w[2], h[2], c);
  c = dot2(w[3], h[3], c);
  return c;
}

__device__ __forceinline__ uint32 pack2(f16 a, f16 b) {
  f16x2 t; t[0] = a; t[1] = b;
  return __builtin_bit_cast(uint32, t);
}

// ---------------------------------------------------------------- setup ----
// whp layout: [kq 0..31][out 0..1023][c 0..3] u32 (f16 pair) -- thread with
// output o reads whp[kq*4096 + o*4 ..] as one coalesced dwordx4.
__global__ __launch_bounds__(256) void setup_weights(
    const float* __restrict__ Wf, const float* __restrict__ Wi,
    const float* __restrict__ Wo, const float* __restrict__ Wc,
    const float* __restrict__ Wout,
    f16* __restrict__ wx16, f16* __restrict__ wout16, uint32* __restrict__ whp)
{
  int id = blockIdx.x * 256 + threadIdx.x;
  const float* WG_[4] = {Wf, Wi, Wo, Wc};
  if (id < 262144) {                       // WxAll f16 [1024][256] (x-part cols)
    int n = id >> 8, k = id & 255;
    int G = n >> 8, j = n & 255;
    wx16[id] = (f16)WG_[G][j * 512 + k];
    return;
  }
  id -= 262144;
  if (id < 65536) { wout16[id] = (f16)Wout[id]; return; }   // Wout f16 [256][256]
  id -= 65536;
  if (id < 131072) {                       // whp: packed f16 h-weights
    int kq = id >> 12, rem = id & 4095;
    int o = rem >> 2, c = rem & 3;
    int G = o >> 8, j = o & 255;
    const float* src = WG_[G] + j * 512 + 256 + kq * 8 + c * 2;
    whp[id] = pack2((f16)src[0], (f16)src[1]);
  }
}

// hbuf: [parity 2][slot 512 = r*8+e][16 u64]; each u64 = 2 tagged u32
// ((tag<<16)|f16), covering cols 32e+2i, 32e+2i+1.
// parity0 = tag0|h0 ; parity1 = sentinel 0xFFFF tags.
__global__ __launch_bounds__(256) void setup_state(
    const float* __restrict__ h0, const float* __restrict__ C0,
    uint64* __restrict__ hbuf, float* __restrict__ c32)
{
  int id = blockIdx.x * 256 + threadIdx.x;
  if (id < 8192) {
    int slot = id >> 4, i = id & 15;
    int r = slot >> 3, e = slot & 7;
    const float* hr = h0 + r * 256 + 32 * e + 2 * i;
    uint32 a = (uint32)__builtin_bit_cast(unsigned short, (f16)hr[0]);
    uint32 b = (uint32)__builtin_bit_cast(unsigned short, (f16)hr[1]);
    hbuf[id] = ((uint64)b << 32) | (uint64)a;
    return;
  }
  id -= 8192;
  if (id < 8192) { hbuf[8192 + id] = 0xFFFF0000FFFF0000ULL; return; }
  id -= 8192;
  if (id < 16384) c32[id] = C0[id];
}

// ---------------------------------------------------------------- GEMM -----
template<int A_F32, int OUT_F32_BIAS>
__global__ __launch_bounds__(256) void gemm_k(
    const void* __restrict__ Av, const f16* __restrict__ B,
    void* __restrict__ Cv, const float* __restrict__ bias, int N)
{
  constexpr int LDA = 264;
  __shared__ f16 As[128 * 264];
  __shared__ f16 Bs[128 * 264];
  const int tid = threadIdx.x;
  const int m0 = blockIdx.x * 128;
  const int n0 = blockIdx.y * 128;

  if (A_F32) {
    const float* A = (const float*)Av;
    #pragma unroll
    for (int j = 0; j < 32; ++j) {
      int flat = (tid + j * 256) * 4;
      int row = flat >> 8, col = flat & 255;
      const float4 v = *(const float4*)(A + (size_t)(m0 + row) * 256 + col);
      uint2 u; u.x = pack2((f16)v.x, (f16)v.y); u.y = pack2((f16)v.z, (f16)v.w);
      *(uint2*)&As[row * LDA + col] = u;
    }
  } else {
    const f16* A = (const f16*)Av;
    #pragma unroll
    for (int j = 0; j < 32; ++j) {
      int flat = (tid + j * 256) * 4;
      int row = flat >> 8, col = flat & 255;
      *(uint2*)&As[row * LDA + col] = *(const uint2*)(A + (size_t)(m0 + row) * 256 + col);
    }
  }
  #pragma unroll
  for (int j = 0; j < 32; ++j) {
    int flat = (tid + j * 256) * 4;
    int row = flat >> 8, col = flat & 255;
    *(uint2*)&Bs[row * LDA + col] = *(const uint2*)(B + (size_t)(n0 + row) * 256 + col);
  }
  __syncthreads();

  const int wave = tid >> 6, l = tid & 63;
  const int wr = wave >> 1, wc = wave & 1;
  const int lr = l & 15, lq = l >> 4;

  f32x4 acc[4][4] = {};
  #pragma unroll
  for (int kk = 0; kk < 8; ++kk) {
    f16x8 a[4], b[4];
    #pragma unroll
    for (int mi = 0; mi < 4; ++mi)
      a[mi] = *(const f16x8*)&As[(64 * wr + 16 * mi + lr) * LDA + kk * 32 + lq * 8];
    #pragma unroll
    for (int ni = 0; ni < 4; ++ni)
      b[ni] = *(const f16x8*)&Bs[(64 * wc + 16 * ni + lr) * LDA + kk * 32 + lq * 8];
    #pragma unroll
    for (int mi = 0; mi < 4; ++mi)
      #pragma unroll
      for (int ni = 0; ni < 4; ++ni)
        acc[mi][ni] = __builtin_amdgcn_mfma_f32_16x16x32_f16(a[mi], b[ni], acc[mi][ni], 0, 0, 0);
  }

  #pragma unroll
  for (int mi = 0; mi < 4; ++mi) {
    #pragma unroll
    for (int ni = 0; ni < 4; ++ni) {
      int col = n0 + 64 * wc + 16 * ni + lr;
      float bv = 0.f;
      if (OUT_F32_BIAS) bv = bias[col];
      #pragma unroll
      for (int v = 0; v < 4; ++v) {
        int row = m0 + 64 * wr + 16 * mi + lq * 4 + v;
        if (OUT_F32_BIAS) ((float*)Cv)[(size_t)row * N + col] = acc[mi][ni][v] + bv;
        else              ((f16*)Cv)[(size_t)row * N + col] = (f16)acc[mi][ni][v];
      }
    }
  }
}

// --------------------------------------------------------- persistent LSTM -
// R18 (compile-fixed): eighth-slice split, all-register weights, 2 WGs/CU.
// 512 WGs x 256 thr; WG w: e = w&7 (col slice [32e,32e+32), all 4 gates),
// r = w>>3. Round-robin grid: CU hosts w and w+256 = DIFFERENT rows ->
// independent recurrences; one WG computes while the other's flight is in
// the air. Thread = (output o_local = tid>>1, K-half kh = tid&1): 16 named
// weight quads (64 VGPR) = ENTIRE slice weights in registers; LDS ~1.2KB.
// Exchange protocol verbatim from the replay-proven R14/R15/R17 family:
// tagged u64 relaxed-agent atomics (tag rides in data), parity ping-pong,
// spin-then-read, tl==0 own-piece path, bounded spins. Degree 7; induction:
// publishing tag t+1 requires consuming all sibs' tag t, which implies every
// sib consumed my tag t-1 from the slot being overwritten.
#define RL16(M) M(0) M(1) M(2) M(3) M(4) M(5) M(6) M(7) M(8) M(9) M(10) M(11) \
  M(12) M(13) M(14) M(15)

__global__ __launch_bounds__(256) void lstm_persist(
    const uint32* __restrict__ whp,
    const float* __restrict__ bf, const float* __restrict__ bi,
    const float* __restrict__ bo, const float* __restrict__ bc,
    const f16* __restrict__ xproj, uint64* __restrict__ hbuf,
    float* __restrict__ c32, float* __restrict__ hid_out,
    f16* __restrict__ h16c, float* __restrict__ cf_out, int t0, int Tc)
{
  __shared__ uint32 h_lds[128] __attribute__((aligned(16))); // full h (256 f16)
  __shared__ float part[132];                                // 128 pre-acts + pad

  const int tid = threadIdx.x;
  const int w = blockIdx.x;
  const int e = w & 7;                    // col-slice [32e, 32e+32)
  const int r = w >> 3;                   // row
  const int o_local = tid >> 1;           // 0..127: gate g, col c
  const int kh = tid & 1;                 // K-half
  const int g = o_local >> 5, c = o_local & 31;
  const int jglob = 32 * e + c;
  const int o_glob = (g << 8) + jglob;

  const u32x4* wq = (const u32x4*)whp;    // [kq*1024 + o]

  // ---- one-time: ALL slice weights in 16 named register quads ----
#define LOADW(i) u32x4 wr##i = wq[(16 * kh + (i)) * 1024 + o_glob];
  RL16(LOADW)
#undef LOADW

  const float* bGp = (g == 0) ? bf : (g == 1) ? bi : (g == 2) ? bo : bc;
  const float biasv = bGp[jglob];

  float Creg = 0.f;
  if (tid < 32) Creg = c32[r * 256 + 32 * e + tid];

  uint64* mybuf = hbuf + (size_t)(r * 8 + e) * 16;   // + parity*8192

  for (int tl = 0; tl < Tc; ++tl) {
    const int gt = t0 + tl;
    const int pp = gt & 1;

    // x-projection load (even lanes; hides under the spin)
    float xpv = 0.f;
    if (!kh) xpv = (float)xproj[((size_t)tl * 64 + r) * 1024 + o_glob];

    // spin: threads 0..111 fetch the 7 sibling pieces (16 u64 each);
    // threads 112..127 fetch own piece at tl==0 (chunk-boundary handoff).
    if (tid < 112) {
      const int s = tid >> 4, i = tid & 15;
      const int ee = s + (s >= e ? 1 : 0);
      const uint64* p = hbuf + (size_t)pp * 8192 + (size_t)(r * 8 + ee) * 16 + i;
      const uint32 tg = (uint32)gt;
      uint64 v = __hip_atomic_load(p, __ATOMIC_RELAXED, __HIP_MEMORY_SCOPE_AGENT);
      int tries = 0;
      while (((((uint32)v) >> 16) != tg || ((uint32)(v >> 48)) != tg) &&
             ++tries < (1 << 22)) {
        v = __hip_atomic_load(p, __ATOMIC_RELAXED, __HIP_MEMORY_SCOPE_AGENT);
      }
      h_lds[16 * ee + i] =
          (((uint32)v) & 0xFFFFu) | ((((uint32)(v >> 32)) & 0xFFFFu) << 16);
    } else if (tl == 0 && tid < 128) {
      const int i = tid - 112;
      const uint64* p = mybuf + (size_t)pp * 8192 + i;
      const uint32 tg = (uint32)gt;
      uint64 v = __hip_atomic_load(p, __ATOMIC_RELAXED, __HIP_MEMORY_SCOPE_AGENT);
      int tries = 0;
      while (((((uint32)v) >> 16) != tg || ((uint32)(v >> 48)) != tg) &&
             ++tries < (1 << 22)) {
        v = __hip_atomic_load(p, __ATOMIC_RELAXED, __HIP_MEMORY_SCOPE_AGENT);
      }
      h_lds[16 * e + i] =
          (((uint32)v) & 0xFFFFu) | ((((uint32)(v >> 32)) & 0xFFFFu) << 16);
    }
    __syncthreads();  // B1

    // dots: 16 register quads over this thread's K-half
    float a0 = 0.f, a1 = 0.f, a2 = 0.f, a3 = 0.f;
#define DOTW(i) { const u32x4 hh = *(const u32x4*)&h_lds[(16 * kh + (i)) * 4]; \
                  float& A_ = (((i) & 3) == 0) ? a0 : (((i) & 3) == 1) ? a1 \
                            : (((i) & 3) == 2) ? a2 : a3; \
                  A_ = dot8(wr##i, hh, A_); }
    RL16(DOTW)
#undef DOTW
    float acc = (a0 + a1) + (a2 + a3);
    acc += __shfl_xor(acc, 1, 64);          // combine K-halves
    if (!kh) part[o_local] = acc + xpv + biasv;
    __syncthreads();  // B2

    // pointwise update + publish (wave 0, lanes 0..31 own one column each)
    if (tid < 32) {
      const float pf = part[tid];
      const float pi = part[32 + tid];
      const float po = part[64 + tid];
      const float pc = part[96 + tid];
      const float f_ = __builtin_amdgcn_rcpf(1.f + __expf(-pf));
      const float i_ = __builtin_amdgcn_rcpf(1.f + __expf(-pi));
      const float o_ = __builtin_amdgcn_rcpf(1.f + __expf(-po));
      const float cb = 1.f - 2.f * __builtin_amdgcn_rcpf(__expf(2.f * pc) + 1.f);
      const float Cn = f_ * Creg + i_ * cb;
      Creg = Cn;
      const float th = 1.f - 2.f * __builtin_amdgcn_rcpf(__expf(2.f * Cn) + 1.f);
      const float hn = o_ * th;
      const int jg = 32 * e + tid;
      hid_out[((size_t)gt * 64 + r) * 256 + jg] = hn;
      const f16 h16v = (f16)hn;
      h16c[((size_t)tl * 64 + r) * 256 + jg] = h16v;
      if (gt == T_STEPS - 1) cf_out[r * 256 + jg] = Cn;

      const uint32 hb = (uint32)__builtin_bit_cast(unsigned short, h16v);
      const uint32 lo = (uint32)__shfl((int)hb, 2 * tid, 64);
      const uint32 hi = (uint32)__shfl((int)hb, 2 * tid + 1, 64);
      if (tid < 16) {
        h_lds[16 * e + tid] = lo | (hi << 16);
        const uint32 tg1u = ((uint32)(gt + 1)) << 16;
        const uint64 v = ((uint64)(hi | tg1u) << 32) | (uint64)(lo | tg1u);
        __hip_atomic_store(mybuf + (size_t)((gt + 1) & 1) * 8192 + tid, v,
                           __ATOMIC_RELAXED, __HIP_MEMORY_SCOPE_AGENT);
      }
    }
    // no barrier here: next iter's B1 orders h_lds[own]/part hazards.
  }

  if (tid < 32) c32[r * 256 + 32 * e + tid] = Creg;
}

// ---------------------------------------------------------------- host -----
extern "C" void kernel_launch(void* const* d_in, const int* in_sizes, int n_in,
                              void* d_out, int out_size, void* d_ws, size_t ws_size,
                              hipStream_t stream)
{
  const float* x    = (const float*)d_in[0];
  const float* h0   = (const float*)d_in[1];
  const float* C0   = (const float*)d_in[2];
  const float* Wf   = (const float*)d_in[3];
  const float* bf   = (const float*)d_in[4];
  const float* Wi   = (const float*)d_in[5];
  const float* bi   = (const float*)d_in[6];
  const float* Wo   = (const float*)d_in[7];
  const float* bo   = (const float*)d_in[8];
  const float* Wc   = (const float*)d_in[9];
  const float* bc   = (const float*)d_in[10];
  const float* Wout = (const float*)d_in[11];
  const float* bout = (const float*)d_in[12];
  float* out = (float*)d_out;

  char* w = (char*)d_ws;
  f16*    wx16   = (f16*)w;    w += (size_t)1024 * 256 * 2;
  f16*    wout16 = (f16*)w;    w += (size_t)256 * 256 * 2;
  uint32* whp    = (uint32*)w; w += (size_t)131072 * 4;
  uint64* hbuf   = (uint64*)w; w += (size_t)2 * 8192 * 8;
  float*  c32    = (float*)w;  w += (size_t)64 * 256 * 4;
  const size_t fixedB = (size_t)(w - (char*)d_ws);

  int Tc = 2;
  const int cands[] = {2048, 1024, 512, 256, 128, 64, 32, 16, 8, 4, 2};
  for (int c : cands) {
    if (fixedB + (size_t)c * 163840 <= ws_size) { Tc = c; break; }
  }

  f16* xproj = (f16*)w;
  f16* h16c  = (f16*)(w + (size_t)Tc * 64 * 1024 * 2);

  setup_weights<<<1792, 256, 0, stream>>>(Wf, Wi, Wo, Wc, Wout,
                                          wx16, wout16, whp);
  setup_state<<<128, 256, 0, stream>>>(h0, C0, hbuf, c32);

  float* hid_out = out + (size_t)T_STEPS * 64 * 256;
  float* cf_out  = out + (size_t)2 * T_STEPS * 64 * 256;

  for (int t0 = 0; t0 < T_STEPS; t0 += Tc) {
    gemm_k<1, 0><<<dim3(Tc * 64 / 128, 8), 256, 0, stream>>>(
        x + (size_t)t0 * 64 * 256, wx16, xproj, nullptr, 1024);
    lstm_persist<<<512, 256, 0, stream>>>(whp, bf, bi, bo, bc,
                                          xproj, hbuf, c32,
                                          hid_out, h16c, cf_out, t0, Tc);
    gemm_k<0, 1><<<dim3(Tc * 64 / 128, 2), 256, 0, stream>>>(
        h16c, wout16, out + (size_t)t0 * 64 * 256, bout, 256);
  }
}